// Round 1
// baseline (180.518 us; speedup 1.0000x reference)
//
#include <hip/hip_runtime.h>
#include <stdint.h>

// conv_59700045414486: y[b,n,o] = sum_{k,c} x[b, kernel2[n,k], c] * W[k,c,o] + bias[o]
// B=64, N=4096, C=64, OUT=64, K2=4  -> per-site GEMM M=64(batch) K=256 N=64(out)
//
// Strategy: bf16 MFMA (16x16x32). W staged once per block into LDS (bf16,
// transposed Wt[o][kk], padded stride). A (gathered x rows) loaded directly
// global->register per K-step (32B/lane contiguous), converted fp32->bf16 via
// v_add(round) + v_perm(pack). 4 sites per block amortize the W stage.
// Memory-bound target: ~128MB HBM => ~20-25us.

#define B_DIM        64
#define N_SITES      4096
#define C_DIM        64
#define OUT_DIM      64
#define SITES_PER_BLOCK 4
#define LDS_STRIDE   264   // 256 + 8 bf16 pad: row stride 132 dwords, %32==4 -> only 2-way (free)

typedef __attribute__((ext_vector_type(8))) short bf16x8;   // 8 bf16 in 4 VGPRs
typedef __attribute__((ext_vector_type(4))) float f32x4;

// round-to-nearest(half-away) fp32->bf16 for two floats, packed into one dword:
// low short = bf16(f0), high short = bf16(f1)
__device__ __forceinline__ uint32_t pack2_bf16(float f0, float f1) {
    uint32_t u0 = __float_as_uint(f0) + 0x8000u;
    uint32_t u1 = __float_as_uint(f1) + 0x8000u;
    // result bytes [3,2,1,0] = [u1.b3, u1.b2, u0.b3, u0.b2]
    return __builtin_amdgcn_perm(u1, u0, 0x07060302u);
}

__global__ __launch_bounds__(256, 4)
void conv_mfma_kernel(const float* __restrict__ x, const float* __restrict__ W,
                      const float* __restrict__ bias, const int* __restrict__ kernel2,
                      float* __restrict__ out)
{
    __shared__ __align__(16) short wt[OUT_DIM * LDS_STRIDE];  // 33792 B

    const int tid  = threadIdx.x;
    const int wave = tid >> 6;       // 0..3 -> batch strip [16*wave, 16*wave+16)
    const int lane = tid & 63;
    const int m    = lane & 15;      // MFMA row (A) / col (B,D) index
    const int q    = lane >> 4;      // quad: k-offset q*8 within frag; D row = q*4+reg

    // ---- Stage W -> LDS as bf16, transposed: wt[o][kk], kk = k*64 + c ----
    // W flat layout is Wf[kk][o] (kk = k*64+c). Thread t: o = t&63, kk in [(t>>6)*64, +64).
    {
        const int o      = tid & 63;
        const int kkbase = (tid >> 6) * 64;
        uint32_t* dst = (uint32_t*)&wt[o * LDS_STRIDE + kkbase];
        #pragma unroll
        for (int j = 0; j < 32; ++j) {
            float f0 = W[(size_t)(kkbase + 2*j    ) * OUT_DIM + o];  // coalesced across lanes (o)
            float f1 = W[(size_t)(kkbase + 2*j + 1) * OUT_DIM + o];
            dst[j] = pack2_bf16(f0, f1);
        }
    }
    __syncthreads();

    // bias: lane's 4 output columns o = t*16 + m (constant across sites)
    float bias_r[4];
    #pragma unroll
    for (int t = 0; t < 4; ++t) bias_r[t] = bias[t*16 + m];

    // lane's x base: batch row (wave*16 + m), k-offset q*8 floats
    const float* xw = x + (size_t)(wave*16 + m) * (N_SITES * C_DIM) + q*8;

    const int site0 = blockIdx.x * SITES_PER_BLOCK;

    for (int si = 0; si < SITES_PER_BLOCK; ++si) {
        const int n = site0 + si;
        const int4 idx = *(const int4*)(kernel2 + n*4);
        const float* bps[4] = {
            xw + (size_t)idx.x * C_DIM,
            xw + (size_t)idx.y * C_DIM,
            xw + (size_t)idx.z * C_DIM,
            xw + (size_t)idx.w * C_DIM
        };

        f32x4 acc[4];
        #pragma unroll
        for (int t = 0; t < 4; ++t) acc[t] = (f32x4){0.f, 0.f, 0.f, 0.f};

        // K = 256 in 8 steps of 32; step s covers kk = s*32..s*32+31 (neighbor k' = s>>1)
        #pragma unroll
        for (int s = 0; s < 8; ++s) {
            const float* p = bps[s >> 1] + (s & 1) * 32;   // + q*8 already in xw; 32B aligned
            f32x4 lo = *(const f32x4*)(p);
            f32x4 hi = *(const f32x4*)(p + 4);

            bf16x8 a;
            uint32_t* ap = (uint32_t*)&a;
            ap[0] = pack2_bf16(lo[0], lo[1]);
            ap[1] = pack2_bf16(lo[2], lo[3]);
            ap[2] = pack2_bf16(hi[0], hi[1]);
            ap[3] = pack2_bf16(hi[2], hi[3]);

            const int col = s*32 + q*8;
            #pragma unroll
            for (int t = 0; t < 4; ++t) {
                // B[k][n]: lane holds n = m, k = q*8+j  ->  wt[o = t*16+m][kk = col+j]
                bf16x8 b = *(const bf16x8*)&wt[(t*16 + m) * LDS_STRIDE + col];
                acc[t] = __builtin_amdgcn_mfma_f32_16x16x32_bf16(a, b, acc[t], 0, 0, 0);
            }
        }

        // D layout: col = m (-> o = t*16+m), row = q*4 + r (-> b = wave*16 + q*4 + r)
        #pragma unroll
        for (int t = 0; t < 4; ++t) {
            #pragma unroll
            for (int r = 0; r < 4; ++r) {
                const size_t b_row = (size_t)(wave*16 + q*4 + r);
                out[(b_row * N_SITES + n) * OUT_DIM + t*16 + m] = acc[t][r] + bias_r[t];
            }
        }
    }
}

extern "C" void kernel_launch(void* const* d_in, const int* in_sizes, int n_in,
                              void* d_out, int out_size, void* d_ws, size_t ws_size,
                              hipStream_t stream) {
    const float* x       = (const float*)d_in[0];
    const float* W       = (const float*)d_in[1];
    const float* bias    = (const float*)d_in[2];
    const int*   kernel2 = (const int*)d_in[3];
    float* out = (float*)d_out;

    conv_mfma_kernel<<<N_SITES / SITES_PER_BLOCK, 256, 0, stream>>>(x, W, bias, kernel2, out);
}